// Round 7
// baseline (379.492 us; speedup 1.0000x reference)
//
#include <hip/hip_runtime.h>
#include <math.h>

// Problem constants: B=4, T=2048, C=1024, NH=16, H=64
#define T_LEN 2048
#define C_DIM 1024
#define C3    3072
#define NHEAD 16
#define HDIM  64

typedef __attribute__((ext_vector_type(8))) __bf16 bf16x8;
typedef __attribute__((ext_vector_type(8))) unsigned short u16x8;
typedef __attribute__((ext_vector_type(4))) float f32x4;
typedef __attribute__((ext_vector_type(2))) unsigned int u32x2;
typedef unsigned short ushort_t;

#define QK_SCALE 0.180336878f   // 1/sqrt(64) * log2(e), folded into Q

#if defined(__has_builtin)
#if __has_builtin(__builtin_amdgcn_exp2f)
#define FAST_EXP2(x) __builtin_amdgcn_exp2f(x)
#endif
#if __has_builtin(__builtin_amdgcn_permlane32_swap) && __has_builtin(__builtin_amdgcn_permlane16_swap)
#define HAVE_PERMLANE_SWAP 1
#endif
#endif
#ifndef FAST_EXP2
#define FAST_EXP2(x) exp2f(x)
#endif

__device__ __forceinline__ ushort_t f2bf(float f) {
    unsigned int u = __float_as_uint(f);
    unsigned int r = (u + 0x7FFFu + ((u >> 16) & 1u)) >> 16;  // RNE
    return (ushort_t)r;
}

#define GLL16(g, l) __builtin_amdgcn_global_load_lds( \
    (const __attribute__((address_space(1))) void*)(g), \
    (__attribute__((address_space(3))) void*)(l), 16, 0, 0)

// ---------------------------------------------------------------------------
// Fused prep: x cast (blocks 0..8191), W_attn transpose (8192..8959),
// W_proj transpose (8960..9215).
// ---------------------------------------------------------------------------
__global__ __launch_bounds__(256) void prep_inputs(
    const float* __restrict__ x, ushort_t* __restrict__ xb,
    const float* __restrict__ W1, ushort_t* __restrict__ Wt1,
    const float* __restrict__ W2, ushort_t* __restrict__ Wt2)
{
    __shared__ float t[64][65];
    const int bx = blockIdx.x;
    if (bx < 8192) {
        const int i = bx * 256 + threadIdx.x;
        const float4 v = ((const float4*)x)[i];
        ushort4 o;
        o.x = f2bf(v.x); o.y = f2bf(v.y); o.z = f2bf(v.z); o.w = f2bf(v.w);
        ((ushort4*)xb)[i] = o;
        return;
    }
    const float* W; ushort_t* Wt; int N, n0, k0;
    if (bx < 8960) {
        const int tt = bx - 8192;
        W = W1; Wt = Wt1; N = C3;
        n0 = (tt % 48) * 64; k0 = (tt / 48) * 64;
    } else {
        const int tt = bx - 8960;
        W = W2; Wt = Wt2; N = C_DIM;
        n0 = (tt % 16) * 64; k0 = (tt / 16) * 64;
    }
    const int K = C_DIM;
    const int c = threadIdx.x & 63, r4 = threadIdx.x >> 6;
#pragma unroll
    for (int i = 0; i < 16; i++) {
        int r = i * 4 + r4;
        t[r][c] = W[(size_t)(k0 + r) * N + n0 + c];
    }
    __syncthreads();
#pragma unroll
    for (int i = 0; i < 16; i++) {
        int r = i * 4 + r4;
        Wt[(size_t)(n0 + r) * K + k0 + c] = f2bf(t[c][r]);
    }
}

// ---------------------------------------------------------------------------
// bf16 MFMA GEMM: 128x128 tile, BK=64, 256 threads, XOR-swizzled unpadded
// LDS staged via global_load_lds width=16. Logical chunk c of row m sits at
// position c^(m&7); frag readers use pos=(4s+quad)^(r16&7) -> uniform banks.
// ---------------------------------------------------------------------------
template <bool OUT_BF16, bool QSCALE>
__global__ __launch_bounds__(256, 3) void gemm_bt_mfma(
    const ushort_t* __restrict__ A, const ushort_t* __restrict__ Bt,
    const float* __restrict__ bias, void* __restrict__ Cv,
    int M, int N, int K)
{
    __shared__ ushort_t Alds[128 * 64];   // 16 KB
    __shared__ ushort_t Blds[128 * 64];   // 16 KB

    const int tid = threadIdx.x;
    const int m0 = blockIdx.y * 128;
    const int n0 = blockIdx.x * 128;
    const int w = tid >> 6;
    const int ln = tid & 63;
    const int quad = ln >> 4;
    const int r16 = ln & 15;
    const int wr0 = (w & 1) * 64;
    const int wc0 = (w >> 1) * 64;

    f32x4 acc[4][4] = {};

    const int srow = tid >> 3;                       // 0..31 (row within round)
    const int csrc8 = ((tid & 7) ^ (srow & 7)) * 8;  // swizzled source elem ofs
    const int sw = r16 & 7;

    for (int k0 = 0; k0 < K; k0 += 64) {
#pragma unroll
        for (int rr = 0; rr < 4; rr++) {
            const ushort_t* ga = A + (size_t)(m0 + rr * 32 + srow) * K + k0 + csrc8;
            GLL16(ga, Alds + rr * 2048 + tid * 8);
            const ushort_t* gb = Bt + (size_t)(n0 + rr * 32 + srow) * K + k0 + csrc8;
            GLL16(gb, Blds + rr * 2048 + tid * 8);
        }
        __syncthreads();

#pragma unroll
        for (int s = 0; s < 2; s++) {
            const int cpos = ((4 * s + quad) ^ sw) * 8;
            bf16x8 af[4], bfr[4];
#pragma unroll
            for (int i = 0; i < 4; i++)
                af[i] = *(const bf16x8*)(Alds + (wr0 + i * 16 + r16) * 64 + cpos);
#pragma unroll
            for (int j = 0; j < 4; j++)
                bfr[j] = *(const bf16x8*)(Blds + (wc0 + j * 16 + r16) * 64 + cpos);
#pragma unroll
            for (int i = 0; i < 4; i++)
#pragma unroll
                for (int j = 0; j < 4; j++)
                    acc[i][j] = __builtin_amdgcn_mfma_f32_16x16x32_bf16(
                        af[i], bfr[j], acc[i][j], 0, 0, 0);
        }
        __syncthreads();
    }

    const float scl = (QSCALE && n0 < C_DIM) ? QK_SCALE : 1.0f;

#pragma unroll
    for (int j = 0; j < 4; j++) {
        const int col = n0 + wc0 + j * 16 + r16;
        const float bv = bias[col];
#pragma unroll
        for (int i = 0; i < 4; i++) {
            const int rowb = m0 + wr0 + i * 16 + quad * 4;
#pragma unroll
            for (int r = 0; r < 4; r++) {
                const float v = (acc[i][j][r] + bv) * scl;
                if (OUT_BF16)
                    ((ushort_t*)Cv)[(size_t)(rowb + r) * N + col] = f2bf(v);
                else
                    ((float*)Cv)[(size_t)(rowb + r) * N + col] = v;
            }
        }
    }
}

// ---------------------------------------------------------------------------
// V pre-transpose: qkv V-slice [b][t][2C + h*64 + d] -> vtg[bh][d][t]
// ---------------------------------------------------------------------------
__global__ __launch_bounds__(256) void transpose_v(
    const ushort_t* __restrict__ qkv, ushort_t* __restrict__ vtg)
{
    __shared__ ushort_t Ts[64][72];
    const int t0 = blockIdx.x * 64;
    const int bh = blockIdx.y;
    const int b = bh >> 4, h = bh & 15;
    const ushort_t* src = qkv + (size_t)b * T_LEN * C3 + 2 * C_DIM + h * HDIM;
    const int tid = threadIdx.x;
    {
        const int r = tid >> 2, cs = (tid & 3) * 16;
        *(u16x8*)(&Ts[r][cs])     = *(const u16x8*)(src + (size_t)(t0 + r) * C3 + cs);
        *(u16x8*)(&Ts[r][cs + 8]) = *(const u16x8*)(src + (size_t)(t0 + r) * C3 + cs + 8);
    }
    __syncthreads();
    {
        const int d = tid >> 2, ts0 = (tid & 3) * 16;
        ushort_t* dst = vtg + ((size_t)bh * HDIM + d) * T_LEN + t0 + ts0;
        u16x8 o0, o1;
#pragma unroll
        for (int j = 0; j < 8; j++) o0[j] = Ts[ts0 + j][d];
#pragma unroll
        for (int j = 0; j < 8; j++) o1[j] = Ts[ts0 + 8 + j][d];
        *(u16x8*)dst = o0;
        *(u16x8*)(dst + 8) = o1;
    }
}

// ---------------------------------------------------------------------------
// MFMA flash attention v10: ALL-REGISTER, ZERO-BARRIER, ZERO-LDS.
// v9's frag values were pure strided global loads behind an LDS swizzle that
// existed only for banking; registers have no banks. Direct loads:
//   ak[s][mb] = K [k0+16mb+r16][32s+8quad ..+7]  (row of qkv K slice)
//   av[s][mb] = Vt[16mb+r16][k0+32s+8quad ..+7]  (row of vtg)
// K double-buffered in registers (prefetch t+1 before computing t; 2x-unrolled
// loop, static buffers per rule #20); V loaded at iteration top, consumed
// after softmax (~400cy of L2 cover). Compiler emits counted vmcnt waits at
// first use. No __syncthreads anywhere; waves free-run (kills the 38%
// all-wave-stall of the barrier-lockstep structure). Head-clustered XCD
// swizzle retained (keeps K/V in the XCD's L2; 4-wave re-load amplification
// is ~32 B/cyc/CU vs 144 available).
// ---------------------------------------------------------------------------

__device__ __forceinline__ void mask_diag(f32x4 (&s)[4], int qloc, int quad)
{
#pragma unroll
    for (int mb = 0; mb < 4; mb++)
#pragma unroll
        for (int r = 0; r < 4; r++)
            if (mb * 16 + quad * 4 + r > qloc) s[mb][r] = -1e30f;
}

// exp2 -> per-lane partial sum -> pack bf16 (RTZ) -> cross-quad permlane
// exchange -> PV B-frags. No LDS.
__device__ __forceinline__ void softmax_exchange(
    f32x4 (&s)[4], float& lacc, bf16x8 (&bp)[2])
{
    unsigned int pk[4][2];
#pragma unroll
    for (int mb = 0; mb < 4; mb++) {
        const float p0 = FAST_EXP2(s[mb][0]);
        const float p1 = FAST_EXP2(s[mb][1]);
        const float p2 = FAST_EXP2(s[mb][2]);
        const float p3 = FAST_EXP2(s[mb][3]);
        lacc += (p0 + p1) + (p2 + p3);
        pk[mb][0] = __builtin_amdgcn_perm(__float_as_uint(p1), __float_as_uint(p0), 0x07060302u);
        pk[mb][1] = __builtin_amdgcn_perm(__float_as_uint(p3), __float_as_uint(p2), 0x07060302u);
    }
#pragma unroll
    for (int s2 = 0; s2 < 2; s2++) {
        uint4 t;
#pragma unroll
        for (int u = 0; u < 2; u++) {
            unsigned int A = pk[2 * s2][u], B = pk[2 * s2 + 1][u];
            unsigned int out1, out2;
#ifdef HAVE_PERMLANE_SWAP
            u32x2 r1 = __builtin_amdgcn_permlane32_swap(A, B, false, false);
            u32x2 r2 = __builtin_amdgcn_permlane16_swap(r1.x, r1.y, false, false);
            out1 = r2.x; out2 = r2.y;
#else
            asm volatile("s_nop 1\n\t"
                         "v_permlane32_swap_b32 %0, %1\n\t"
                         "s_nop 1\n\t"
                         "v_permlane16_swap_b32 %0, %1"
                         : "+v"(A), "+v"(B));
            out1 = A; out2 = B;
#endif
            if (u == 0) { t.x = out1; t.z = out2; }
            else        { t.y = out1; t.w = out2; }
        }
        bp[s2] = *(bf16x8*)&t;
    }
}

struct AttnCtx {
    const ushort_t* basek;
    const ushort_t* vrow;
    int i, lastkt, qloc, quad, r16, dq;
    bf16x8 aqA[2], aqB[2];
    f32x4 oA[4], oB[4];
    float lA, lB;
};

// Load K frags for k-tile kt into kf (8 x global_load_dwordx4, no waits here).
__device__ __forceinline__ void issue_k(AttnCtx& c, bf16x8 (&kf)[2][4], int kt)
{
    const ushort_t* p = c.basek + (size_t)(kt * 64 + c.r16) * C3 + c.dq;
#pragma unroll
    for (int s = 0; s < 2; s++)
#pragma unroll
        for (int mb = 0; mb < 4; mb++)
            kf[s][mb] = *(const bf16x8*)(p + (size_t)(mb * 16) * C3 + s * 32);
}

// Load V^T frags for k-tile kt.
__device__ __forceinline__ void issue_v(AttnCtx& c, bf16x8 (&vf)[2][4], int kt)
{
    const ushort_t* p = c.vrow + (size_t)c.r16 * T_LEN + kt * 64 + c.dq;
#pragma unroll
    for (int s = 0; s < 2; s++)
#pragma unroll
        for (int mb = 0; mb < 4; mb++)
            vf[s][mb] = *(const bf16x8*)(p + (size_t)(mb * 16) * T_LEN + s * 32);
}

// One k-tile iteration: QK^T -> mask -> softmax+exchange -> PV.
__device__ __forceinline__ void attn_body(
    AttnCtx& c, const bf16x8 (&kf)[2][4], const bf16x8 (&vf)[2][4], int kt)
{
    if (kt <= c.i) {
        // ---- both halves active ----
        f32x4 sA[4] = {}, sB[4] = {};
#pragma unroll
        for (int s = 0; s < 2; s++)
#pragma unroll
            for (int mb = 0; mb < 4; mb++) {
                sA[mb] = __builtin_amdgcn_mfma_f32_16x16x32_bf16(kf[s][mb], c.aqA[s], sA[mb], 0, 0, 0);
                sB[mb] = __builtin_amdgcn_mfma_f32_16x16x32_bf16(kf[s][mb], c.aqB[s], sB[mb], 0, 0, 0);
            }
        if (kt == c.i) mask_diag(sA, c.qloc, c.quad);
        bf16x8 bpA[2], bpB[2];
        softmax_exchange(sA, c.lA, bpA);
        softmax_exchange(sB, c.lB, bpB);
#pragma unroll
        for (int s = 0; s < 2; s++)
#pragma unroll
            for (int mb = 0; mb < 4; mb++) {
                c.oA[mb] = __builtin_amdgcn_mfma_f32_16x16x32_bf16(vf[s][mb], bpA[s], c.oA[mb], 0, 0, 0);
                c.oB[mb] = __builtin_amdgcn_mfma_f32_16x16x32_bf16(vf[s][mb], bpB[s], c.oB[mb], 0, 0, 0);
            }
    } else {
        // ---- B-half only ----
        f32x4 sB[4] = {};
#pragma unroll
        for (int s = 0; s < 2; s++)
#pragma unroll
            for (int mb = 0; mb < 4; mb++)
                sB[mb] = __builtin_amdgcn_mfma_f32_16x16x32_bf16(kf[s][mb], c.aqB[s], sB[mb], 0, 0, 0);
        if (kt == c.lastkt) mask_diag(sB, c.qloc, c.quad);
        bf16x8 bpB[2];
        softmax_exchange(sB, c.lB, bpB);
#pragma unroll
        for (int s = 0; s < 2; s++)
#pragma unroll
            for (int mb = 0; mb < 4; mb++)
                c.oB[mb] = __builtin_amdgcn_mfma_f32_16x16x32_bf16(vf[s][mb], bpB[s], c.oB[mb], 0, 0, 0);
    }
}

__global__ __launch_bounds__(256, 2) void attn_flash_mfma5(
    const ushort_t* __restrict__ qkv, const ushort_t* __restrict__ vtg,
    ushort_t* __restrict__ y)
{
    // ---- head-clustered XCD swizzle (v9) ----
    const int bid = blockIdx.x;            // 0..1023
    const int i = (bid >> 3) >> 3;         // pair index 0..15
    const int bh = (bid & 7) * 8 + ((bid >> 3) & 7);
    const int b = bh >> 4, h = bh & 15;
    const int qA0 = i * 64;
    const int qB0 = (31 - i) * 64;

    const int tid = threadIdx.x;
    const int w = tid >> 6;
    const int ln = tid & 63;
    const int quad = ln >> 4;
    const int r16 = ln & 15;
    const int qloc = w * 16 + r16;

    const ushort_t* baseq = qkv + (size_t)b * T_LEN * C3 + h * HDIM;

    AttnCtx c;
    c.basek = baseq + C_DIM;
    c.vrow  = vtg + (size_t)bh * HDIM * T_LEN;
    c.i = i; c.lastkt = 31 - i;
    c.qloc = qloc; c.quad = quad; c.r16 = r16; c.dq = quad * 8;
    c.lA = 0.0f; c.lB = 0.0f;
#pragma unroll
    for (int mb = 0; mb < 4; mb++) { c.oA[mb] = (f32x4){}; c.oB[mb] = (f32x4){}; }

    // ---- Q frags (one-time) + K(0) prefetch ----
    bf16x8 kf0[2][4], kf1[2][4], vf[2][4];
    issue_k(c, kf0, 0);
#pragma unroll
    for (int s = 0; s < 2; s++) {
        c.aqA[s] = *(const bf16x8*)(baseq + (size_t)(qA0 + qloc) * C3 + s * 32 + c.dq);
        c.aqB[s] = *(const bf16x8*)(baseq + (size_t)(qB0 + qloc) * C3 + s * 32 + c.dq);
    }

    // ---- 2x-unrolled free-running loop (static K double-buffer) ----
    int kt = 0;
    while (true) {
        // iteration kt: uses kf0
        if (kt + 1 <= c.lastkt) issue_k(c, kf1, kt + 1);
        issue_v(c, vf, kt);
        attn_body(c, kf0, vf, kt);
        if (++kt > c.lastkt) break;

        // iteration kt: uses kf1
        if (kt + 1 <= c.lastkt) issue_k(c, kf0, kt + 1);
        issue_v(c, vf, kt);
        attn_body(c, kf1, vf, kt);
        if (++kt > c.lastkt) break;
    }

    // ---- epilogue: reduce l across the 4 lanes sharing each q, store ----
    float lA = c.lA, lB = c.lB;
    lA += __shfl_xor(lA, 16); lA += __shfl_xor(lA, 32);
    lB += __shfl_xor(lB, 16); lB += __shfl_xor(lB, 32);
    {
        const float invA = 1.0f / lA;
        ushort_t* yp = y + ((size_t)(b * T_LEN + qA0 + qloc)) * C_DIM + h * HDIM;
#pragma unroll
        for (int mb = 0; mb < 4; mb++) {
            ushort4 o;
            o.x = f2bf(c.oA[mb][0] * invA);
            o.y = f2bf(c.oA[mb][1] * invA);
            o.z = f2bf(c.oA[mb][2] * invA);
            o.w = f2bf(c.oA[mb][3] * invA);
            *(ushort4*)(yp + mb * 16 + quad * 4) = o;
        }
    }
    {
        const float invB = 1.0f / lB;
        ushort_t* yp = y + ((size_t)(b * T_LEN + qB0 + qloc)) * C_DIM + h * HDIM;
#pragma unroll
        for (int mb = 0; mb < 4; mb++) {
            ushort4 o;
            o.x = f2bf(c.oB[mb][0] * invB);
            o.y = f2bf(c.oB[mb][1] * invB);
            o.z = f2bf(c.oB[mb][2] * invB);
            o.w = f2bf(c.oB[mb][3] * invB);
            *(ushort4*)(yp + mb * 16 + quad * 4) = o;
        }
    }
}

// ---------------------------------------------------------------------------
extern "C" void kernel_launch(void* const* d_in, const int* in_sizes, int n_in,
                              void* d_out, int out_size, void* d_ws, size_t ws_size,
                              hipStream_t stream)
{
    const float* x      = (const float*)d_in[0];
    const float* W_attn = (const float*)d_in[1];
    const float* b_attn = (const float*)d_in[2];
    const float* W_proj = (const float*)d_in[3];
    const float* b_proj = (const float*)d_in[4];
    float* out = (float*)d_out;

    const int M = 4 * T_LEN;  // 8192
    char* ws = (char*)d_ws;
    ushort_t* qkv = (ushort_t*)ws;
    ushort_t* xb  = (ushort_t*)(ws + 50331648);
    ushort_t* Wt1 = (ushort_t*)(ws + 67108864);
    ushort_t* yb  = (ushort_t*)(ws + 73400320);
    ushort_t* Wt2 = (ushort_t*)(ws + 90177536);
    ushort_t* vtg = (ushort_t*)(ws + 92274688);

    prep_inputs<<<9216, 256, 0, stream>>>(x, xb, W_attn, Wt1, W_proj, Wt2);

    // 1) qkv = x @ W_attn + b_attn  (bf16; Q slice pre-scaled by QK_SCALE)
    gemm_bt_mfma<true, true><<<dim3(C3 / 128, M / 128), 256, 0, stream>>>(
        xb, Wt1, b_attn, qkv, M, C3, C_DIM);

    transpose_v<<<dim3(T_LEN / 64, 4 * NHEAD), 256, 0, stream>>>(qkv, vtg);

    // 2) causal flash attention (all-register, barrier-free) -> yb bf16
    attn_flash_mfma5<<<dim3(1024), 256, 0, stream>>>(qkv, vtg, yb);

    // 3) out = y @ W_proj + b_proj  (f32 out)
    gemm_bt_mfma<false, false><<<dim3(C_DIM / 128, M / 128), 256, 0, stream>>>(
        yb, Wt2, b_proj, out, M, C_DIM, C_DIM);
}

// Round 8
// 254.003 us; speedup vs baseline: 1.4940x; 1.4940x over previous
//
#include <hip/hip_runtime.h>
#include <math.h>

// Problem constants: B=4, T=2048, C=1024, NH=16, H=64
#define T_LEN 2048
#define C_DIM 1024
#define C3    3072
#define NHEAD 16
#define HDIM  64

typedef __attribute__((ext_vector_type(8))) __bf16 bf16x8;
typedef __attribute__((ext_vector_type(8))) unsigned short u16x8;
typedef __attribute__((ext_vector_type(4))) float f32x4;
typedef __attribute__((ext_vector_type(2))) unsigned int u32x2;
typedef unsigned short ushort_t;

#define QK_SCALE 0.180336878f   // 1/sqrt(64) * log2(e), folded into Q

#if defined(__has_builtin)
#if __has_builtin(__builtin_amdgcn_exp2f)
#define FAST_EXP2(x) __builtin_amdgcn_exp2f(x)
#endif
#if __has_builtin(__builtin_amdgcn_permlane32_swap) && __has_builtin(__builtin_amdgcn_permlane16_swap)
#define HAVE_PERMLANE_SWAP 1
#endif
#endif
#ifndef FAST_EXP2
#define FAST_EXP2(x) exp2f(x)
#endif

__device__ __forceinline__ ushort_t f2bf(float f) {
    unsigned int u = __float_as_uint(f);
    unsigned int r = (u + 0x7FFFu + ((u >> 16) & 1u)) >> 16;  // RNE
    return (ushort_t)r;
}

#define GLL16(g, l) __builtin_amdgcn_global_load_lds( \
    (const __attribute__((address_space(1))) void*)(g), \
    (__attribute__((address_space(3))) void*)(l), 16, 0, 0)

// ---------------------------------------------------------------------------
// Fused prep: x cast (blocks 0..8191), W_attn transpose (8192..8959),
// W_proj transpose (8960..9215).
// ---------------------------------------------------------------------------
__global__ __launch_bounds__(256) void prep_inputs(
    const float* __restrict__ x, ushort_t* __restrict__ xb,
    const float* __restrict__ W1, ushort_t* __restrict__ Wt1,
    const float* __restrict__ W2, ushort_t* __restrict__ Wt2)
{
    __shared__ float t[64][65];
    const int bx = blockIdx.x;
    if (bx < 8192) {
        const int i = bx * 256 + threadIdx.x;
        const float4 v = ((const float4*)x)[i];
        ushort4 o;
        o.x = f2bf(v.x); o.y = f2bf(v.y); o.z = f2bf(v.z); o.w = f2bf(v.w);
        ((ushort4*)xb)[i] = o;
        return;
    }
    const float* W; ushort_t* Wt; int N, n0, k0;
    if (bx < 8960) {
        const int tt = bx - 8192;
        W = W1; Wt = Wt1; N = C3;
        n0 = (tt % 48) * 64; k0 = (tt / 48) * 64;
    } else {
        const int tt = bx - 8960;
        W = W2; Wt = Wt2; N = C_DIM;
        n0 = (tt % 16) * 64; k0 = (tt / 16) * 64;
    }
    const int K = C_DIM;
    const int c = threadIdx.x & 63, r4 = threadIdx.x >> 6;
#pragma unroll
    for (int i = 0; i < 16; i++) {
        int r = i * 4 + r4;
        t[r][c] = W[(size_t)(k0 + r) * N + n0 + c];
    }
    __syncthreads();
#pragma unroll
    for (int i = 0; i < 16; i++) {
        int r = i * 4 + r4;
        Wt[(size_t)(n0 + r) * K + k0 + c] = f2bf(t[c][r]);
    }
}

// ---------------------------------------------------------------------------
// bf16 MFMA GEMM: 128x128 tile, BK=64, 256 threads, XOR-swizzled unpadded
// LDS staged via global_load_lds width=16. Logical chunk c of row m sits at
// position c^(m&7); frag readers use pos=(4s+quad)^(r16&7) -> uniform banks.
// v11: 1D grid + XCD row-clustering: xcd=bid&7, j=bid>>3, row-tile
// ty=xcd*8+(j&7), col-tile tx=j>>3. Each XCD owns 8 A-row-panels (2 MB,
// L2-resident, reused nbx times); bijective (M/128=64=8x8).
// ---------------------------------------------------------------------------
template <bool OUT_BF16, bool QSCALE>
__global__ __launch_bounds__(256, 3) void gemm_bt_mfma(
    const ushort_t* __restrict__ A, const ushort_t* __restrict__ Bt,
    const float* __restrict__ bias, void* __restrict__ Cv,
    int M, int N, int K)
{
    __shared__ ushort_t Alds[128 * 64];   // 16 KB
    __shared__ ushort_t Blds[128 * 64];   // 16 KB

    const int tid = threadIdx.x;
    const int bid = blockIdx.x;
    const int jj = bid >> 3;
    const int m0 = (((bid & 7) << 3) | (jj & 7)) * 128;   // row tile
    const int n0 = (jj >> 3) * 128;                       // col tile
    const int w = tid >> 6;
    const int ln = tid & 63;
    const int quad = ln >> 4;
    const int r16 = ln & 15;
    const int wr0 = (w & 1) * 64;
    const int wc0 = (w >> 1) * 64;

    f32x4 acc[4][4] = {};

    const int srow = tid >> 3;                       // 0..31 (row within round)
    const int csrc8 = ((tid & 7) ^ (srow & 7)) * 8;  // swizzled source elem ofs
    const int sw = r16 & 7;

    for (int k0 = 0; k0 < K; k0 += 64) {
#pragma unroll
        for (int rr = 0; rr < 4; rr++) {
            const ushort_t* ga = A + (size_t)(m0 + rr * 32 + srow) * K + k0 + csrc8;
            GLL16(ga, Alds + rr * 2048 + tid * 8);
            const ushort_t* gb = Bt + (size_t)(n0 + rr * 32 + srow) * K + k0 + csrc8;
            GLL16(gb, Blds + rr * 2048 + tid * 8);
        }
        __syncthreads();

#pragma unroll
        for (int s = 0; s < 2; s++) {
            const int cpos = ((4 * s + quad) ^ sw) * 8;
            bf16x8 af[4], bfr[4];
#pragma unroll
            for (int i = 0; i < 4; i++)
                af[i] = *(const bf16x8*)(Alds + (wr0 + i * 16 + r16) * 64 + cpos);
#pragma unroll
            for (int j = 0; j < 4; j++)
                bfr[j] = *(const bf16x8*)(Blds + (wc0 + j * 16 + r16) * 64 + cpos);
#pragma unroll
            for (int i = 0; i < 4; i++)
#pragma unroll
                for (int j = 0; j < 4; j++)
                    acc[i][j] = __builtin_amdgcn_mfma_f32_16x16x32_bf16(
                        af[i], bfr[j], acc[i][j], 0, 0, 0);
        }
        __syncthreads();
    }

    const float scl = (QSCALE && n0 < C_DIM) ? QK_SCALE : 1.0f;

#pragma unroll
    for (int j = 0; j < 4; j++) {
        const int col = n0 + wc0 + j * 16 + r16;
        const float bv = bias[col];
#pragma unroll
        for (int i = 0; i < 4; i++) {
            const int rowb = m0 + wr0 + i * 16 + quad * 4;
#pragma unroll
            for (int r = 0; r < 4; r++) {
                const float v = (acc[i][j][r] + bv) * scl;
                if (OUT_BF16)
                    ((ushort_t*)Cv)[(size_t)(rowb + r) * N + col] = f2bf(v);
                else
                    ((float*)Cv)[(size_t)(rowb + r) * N + col] = v;
            }
        }
    }
}

// ---------------------------------------------------------------------------
// V pre-transpose: qkv V-slice [b][t][2C + h*64 + d] -> vtg[bh][d][t]
// ---------------------------------------------------------------------------
__global__ __launch_bounds__(256) void transpose_v(
    const ushort_t* __restrict__ qkv, ushort_t* __restrict__ vtg)
{
    __shared__ ushort_t Ts[64][72];
    const int t0 = blockIdx.x * 64;
    const int bh = blockIdx.y;
    const int b = bh >> 4, h = bh & 15;
    const ushort_t* src = qkv + (size_t)b * T_LEN * C3 + 2 * C_DIM + h * HDIM;
    const int tid = threadIdx.x;
    {
        const int r = tid >> 2, cs = (tid & 3) * 16;
        *(u16x8*)(&Ts[r][cs])     = *(const u16x8*)(src + (size_t)(t0 + r) * C3 + cs);
        *(u16x8*)(&Ts[r][cs + 8]) = *(const u16x8*)(src + (size_t)(t0 + r) * C3 + cs + 8);
    }
    __syncthreads();
    {
        const int d = tid >> 2, ts0 = (tid & 3) * 16;
        ushort_t* dst = vtg + ((size_t)bh * HDIM + d) * T_LEN + t0 + ts0;
        u16x8 o0, o1;
#pragma unroll
        for (int j = 0; j < 8; j++) o0[j] = Ts[ts0 + j][d];
#pragma unroll
        for (int j = 0; j < 8; j++) o1[j] = Ts[ts0 + 8 + j][d];
        *(u16x8*)dst = o0;
        *(u16x8*)(dst + 8) = o1;
    }
}

// ---------------------------------------------------------------------------
// MFMA flash attention v9 (reverted from v10 regression): in-register P
// exchange, K+V double-buffered in LDS via global_load_lds (coalescing is
// the point of the LDS staging -- v10 proved per-wave register loads are
// latency-death), one barrier/iter, 32 KB LDS, head-clustered XCD swizzle.
// ---------------------------------------------------------------------------

__device__ __forceinline__ void mask_diag(f32x4 (&s)[4], int qloc, int quad)
{
#pragma unroll
    for (int mb = 0; mb < 4; mb++)
#pragma unroll
        for (int r = 0; r < 4; r++)
            if (mb * 16 + quad * 4 + r > qloc) s[mb][r] = -1e30f;
}

// exp2 -> per-lane partial sum -> pack bf16 (RTZ) -> cross-quad permlane
// exchange -> PV B-frags. No LDS.
__device__ __forceinline__ void softmax_exchange(
    f32x4 (&s)[4], float& lacc, bf16x8 (&bp)[2])
{
    unsigned int pk[4][2];
#pragma unroll
    for (int mb = 0; mb < 4; mb++) {
        const float p0 = FAST_EXP2(s[mb][0]);
        const float p1 = FAST_EXP2(s[mb][1]);
        const float p2 = FAST_EXP2(s[mb][2]);
        const float p3 = FAST_EXP2(s[mb][3]);
        lacc += (p0 + p1) + (p2 + p3);
        pk[mb][0] = __builtin_amdgcn_perm(__float_as_uint(p1), __float_as_uint(p0), 0x07060302u);
        pk[mb][1] = __builtin_amdgcn_perm(__float_as_uint(p3), __float_as_uint(p2), 0x07060302u);
    }
#pragma unroll
    for (int s2 = 0; s2 < 2; s2++) {
        uint4 t;
#pragma unroll
        for (int u = 0; u < 2; u++) {
            unsigned int A = pk[2 * s2][u], B = pk[2 * s2 + 1][u];
            unsigned int out1, out2;
#ifdef HAVE_PERMLANE_SWAP
            u32x2 r1 = __builtin_amdgcn_permlane32_swap(A, B, false, false);
            u32x2 r2 = __builtin_amdgcn_permlane16_swap(r1.x, r1.y, false, false);
            out1 = r2.x; out2 = r2.y;
#else
            asm volatile("s_nop 1\n\t"
                         "v_permlane32_swap_b32 %0, %1\n\t"
                         "s_nop 1\n\t"
                         "v_permlane16_swap_b32 %0, %1"
                         : "+v"(A), "+v"(B));
            out1 = A; out2 = B;
#endif
            if (u == 0) { t.x = out1; t.z = out2; }
            else        { t.y = out1; t.w = out2; }
        }
        bp[s2] = *(bf16x8*)&t;
    }
}

// Issue the 2 global_load_lds for K tile [k][d] of iteration kt_ into
// double-buffer half buf_. No waits.
#define STAGE_K(kt_, buf_) do {                                               \
    const int _k0 = (kt_) * 64;                                               \
    const int _bo = (buf_) * 4096;                                            \
    _Pragma("unroll")                                                         \
    for (int rr = 0; rr < 2; rr++) {                                          \
        const ushort_t* gk = basek + (size_t)(_k0 + rr * 32 + srow) * C3 + csrc8; \
        GLL16(gk, Ks + _bo + rr * 2048 + tid * 8);                            \
    }                                                                         \
} while (0)

// Same for Vt tile [d][k].
#define STAGE_V(kt_, buf_) do {                                               \
    const int _k0 = (kt_) * 64;                                               \
    const int _bo = (buf_) * 4096;                                            \
    _Pragma("unroll")                                                         \
    for (int rr = 0; rr < 2; rr++) {                                          \
        const ushort_t* gv = vrow + (size_t)(rr * 32 + srow) * T_LEN + _k0 + csrc8; \
        GLL16(gv, Vs + _bo + rr * 2048 + tid * 8);                            \
    }                                                                         \
} while (0)

__global__ __launch_bounds__(256, 4) void attn_flash_mfma5(
    const ushort_t* __restrict__ qkv, const ushort_t* __restrict__ vtg,
    ushort_t* __restrict__ y)
{
    __shared__ ushort_t Ks[2 * 64 * 64];  // 16 KB, double-buffered, XOR swizzle
    __shared__ ushort_t Vs[2 * 64 * 64];  // 16 KB, double-buffered, Vt [d][k]

    // ---- head-clustered XCD swizzle ----
    const int bid = blockIdx.x;            // 0..1023
    const int i = (bid >> 3) >> 3;         // pair index 0..15
    const int bh = (bid & 7) * 8 + ((bid >> 3) & 7);
    const int b = bh >> 4, h = bh & 15;
    const int qA0 = i * 64;
    const int qB0 = (31 - i) * 64;
    const int lastkt = 31 - i;

    const int tid = threadIdx.x;
    const int w = tid >> 6;
    const int ln = tid & 63;
    const int quad = ln >> 4;
    const int r16 = ln & 15;
    const int qloc = w * 16 + r16;
    const int sw = r16 & 7;

    const int srow = tid >> 3;                       // 0..31
    const int csrc8 = ((tid & 7) ^ (srow & 7)) * 8;  // swizzled source chunk
    const int cpos0 = (quad ^ sw) * 8;               // s=0 read pos; s=1: ^32

    const ushort_t* baseq = qkv + (size_t)b * T_LEN * C3 + h * HDIM;
    const ushort_t* basek = baseq + C_DIM;
    const ushort_t* vrow = vtg + (size_t)bh * HDIM * T_LEN;

    // ---- stage K(0)/V(0) into buffer 0; Q frags straight from global ----
    STAGE_K(0, 0);
    STAGE_V(0, 0);

    bf16x8 aqA[2], aqB[2];
#pragma unroll
    for (int s = 0; s < 2; s++) {
        aqA[s] = *(const bf16x8*)(baseq + (size_t)(qA0 + qloc) * C3 + s * 32 + quad * 8);
        aqB[s] = *(const bf16x8*)(baseq + (size_t)(qB0 + qloc) * C3 + s * 32 + quad * 8);
    }

    f32x4 oA[4] = {}, oB[4] = {};
    float lA = 0.0f, lB = 0.0f;            // per-lane partials; reduced at end

    for (int kt = 0; kt <= lastkt; kt++) {
        // Single barrier per iteration: its implicit vmcnt(0) drains
        // K/V(kt) -- staged one full iteration ago (covered) -- and its
        // lgkmcnt(0) closes all reads of the buffer being overwritten below.
        __syncthreads();

        if (kt < lastkt) {
            STAGE_K(kt + 1, (kt + 1) & 1);
            STAGE_V(kt + 1, (kt + 1) & 1);
        }

        const int kb = (kt & 1) * 4096;

        if (kt <= i) {
            // ---- both halves active (shared ak / av frags) ----
            f32x4 sA[4] = {}, sB[4] = {};
#pragma unroll
            for (int s = 0; s < 2; s++)
#pragma unroll
                for (int mb = 0; mb < 4; mb++) {
                    const bf16x8 ak = *(const bf16x8*)(Ks + kb + (mb * 16 + r16) * 64 + (cpos0 ^ (s * 32)));
                    sA[mb] = __builtin_amdgcn_mfma_f32_16x16x32_bf16(ak, aqA[s], sA[mb], 0, 0, 0);
                    sB[mb] = __builtin_amdgcn_mfma_f32_16x16x32_bf16(ak, aqB[s], sB[mb], 0, 0, 0);
                }
            if (kt == i) mask_diag(sA, qloc, quad);
            bf16x8 bpA[2], bpB[2];
            softmax_exchange(sA, lA, bpA);
            softmax_exchange(sB, lB, bpB);
#pragma unroll
            for (int s = 0; s < 2; s++)
#pragma unroll
                for (int mb = 0; mb < 4; mb++) {
                    const bf16x8 av = *(const bf16x8*)(Vs + kb + (mb * 16 + r16) * 64 + (cpos0 ^ (s * 32)));
                    oA[mb] = __builtin_amdgcn_mfma_f32_16x16x32_bf16(av, bpA[s], oA[mb], 0, 0, 0);
                    oB[mb] = __builtin_amdgcn_mfma_f32_16x16x32_bf16(av, bpB[s], oB[mb], 0, 0, 0);
                }
        } else {
            // ---- B-half only ----
            f32x4 sB[4] = {};
#pragma unroll
            for (int s = 0; s < 2; s++)
#pragma unroll
                for (int mb = 0; mb < 4; mb++) {
                    const bf16x8 ak = *(const bf16x8*)(Ks + kb + (mb * 16 + r16) * 64 + (cpos0 ^ (s * 32)));
                    sB[mb] = __builtin_amdgcn_mfma_f32_16x16x32_bf16(ak, aqB[s], sB[mb], 0, 0, 0);
                }
            if (kt == lastkt) mask_diag(sB, qloc, quad);
            bf16x8 bpB[2];
            softmax_exchange(sB, lB, bpB);
#pragma unroll
            for (int s = 0; s < 2; s++)
#pragma unroll
                for (int mb = 0; mb < 4; mb++) {
                    const bf16x8 av = *(const bf16x8*)(Vs + kb + (mb * 16 + r16) * 64 + (cpos0 ^ (s * 32)));
                    oB[mb] = __builtin_amdgcn_mfma_f32_16x16x32_bf16(av, bpB[s], oB[mb], 0, 0, 0);
                }
        }
    }

    // ---- epilogue: reduce l across the 4 lanes sharing each q, store ----
    lA += __shfl_xor(lA, 16); lA += __shfl_xor(lA, 32);
    lB += __shfl_xor(lB, 16); lB += __shfl_xor(lB, 32);
    {
        const float invA = 1.0f / lA;
        ushort_t* yp = y + ((size_t)(b * T_LEN + qA0 + qloc)) * C_DIM + h * HDIM;
#pragma unroll
        for (int mb = 0; mb < 4; mb++) {
            ushort4 o;
            o.x = f2bf(oA[mb][0] * invA);
            o.y = f2bf(oA[mb][1] * invA);
            o.z = f2bf(oA[mb][2] * invA);
            o.w = f2bf(oA[mb][3] * invA);
            *(ushort4*)(yp + mb * 16 + quad * 4) = o;
        }
    }
    {
        const float invB = 1.0f / lB;
        ushort_t* yp = y + ((size_t)(b * T_LEN + qB0 + qloc)) * C_DIM + h * HDIM;
#pragma unroll
        for (int mb = 0; mb < 4; mb++) {
            ushort4 o;
            o.x = f2bf(oB[mb][0] * invB);
            o.y = f2bf(oB[mb][1] * invB);
            o.z = f2bf(oB[mb][2] * invB);
            o.w = f2bf(oB[mb][3] * invB);
            *(ushort4*)(yp + mb * 16 + quad * 4) = o;
        }
    }
}

// ---------------------------------------------------------------------------
extern "C" void kernel_launch(void* const* d_in, const int* in_sizes, int n_in,
                              void* d_out, int out_size, void* d_ws, size_t ws_size,
                              hipStream_t stream)
{
    const float* x      = (const float*)d_in[0];
    const float* W_attn = (const float*)d_in[1];
    const float* b_attn = (const float*)d_in[2];
    const float* W_proj = (const float*)d_in[3];
    const float* b_proj = (const float*)d_in[4];
    float* out = (float*)d_out;

    const int M = 4 * T_LEN;  // 8192
    char* ws = (char*)d_ws;
    ushort_t* qkv = (ushort_t*)ws;
    ushort_t* xb  = (ushort_t*)(ws + 50331648);
    ushort_t* Wt1 = (ushort_t*)(ws + 67108864);
    ushort_t* yb  = (ushort_t*)(ws + 73400320);
    ushort_t* Wt2 = (ushort_t*)(ws + 90177536);
    ushort_t* vtg = (ushort_t*)(ws + 92274688);

    prep_inputs<<<9216, 256, 0, stream>>>(x, xb, W_attn, Wt1, W_proj, Wt2);

    // 1) qkv = x @ W_attn + b_attn (bf16; Q pre-scaled). 1D grid, XCD-clustered.
    gemm_bt_mfma<true, true><<<dim3((M / 128) * (C3 / 128)), 256, 0, stream>>>(
        xb, Wt1, b_attn, qkv, M, C3, C_DIM);

    transpose_v<<<dim3(T_LEN / 64, 4 * NHEAD), 256, 0, stream>>>(qkv, vtg);

    // 2) causal flash attention (v9) -> yb bf16
    attn_flash_mfma5<<<dim3(1024), 256, 0, stream>>>(qkv, vtg, yb);

    // 3) out = y @ W_proj + b_proj (f32 out). 1D grid, XCD-clustered.
    gemm_bt_mfma<false, false><<<dim3((M / 128) * (C_DIM / 128)), 256, 0, stream>>>(
        yb, Wt2, b_proj, out, M, C_DIM, C_DIM);
}